// Round 10
// baseline (134.968 us; speedup 1.0000x reference)
//
#include <hip/hip_runtime.h>

// SINDy: out[65536,32] = Theta(z)[65536,6545] @ (Xi*Xi_mask)[6545,32]
// Round-27: 512-thread blocks, 8-way k-split — combine R26's low B-traffic
// (128-row blocks, 289MB) with R23-level TLP (4 waves/SIMD).
//  - R26 post-mortem: traffic halved but occupancy fell to 2 waves/SIMD;
//    VALU(~17us) + MFMA(~15us) + L2(8us) still SUM (45.4us wall) because
//    one wave's VALU->MFMA chain has no partner to overlap with.
//  - R24 bought occupancy with traffic (failed); R26 bought traffic with
//    occupancy (flat). This round: 8 waves/block x 512 blocks = traffic
//    unchanged, waves/SIMD doubled. K cut at even quarter-compatible
//    boundaries {0,70,138,208,276,346,414,484,552}; only wave 7 peels.
//  - Combine: two parallel LDS chains (hi: kh7 w, kh6/5/4 +=; lo: kh3 w,
//    kh2/1 +=), kh0 final = acc+lo+hi+bias. 5 rounds, 4 syncs, +16KB LDS
//    (53.4KB/block x 2 blocks/CU = 107KB < 160).
// MFMA 32x32x16 layouts (dtype-independent, verified rounds 1-14):
//   A[m][k]: m=lane&31, k=(lane>>5)*8+jj   (reg q: lo=k 2q, hi=k 2q+1)
//   B[k][n]: n=lane&31, k=(lane>>5)*8+jj
//   C/D:     col=lane&31, row=(reg&3)+8*(reg>>2)+4*(lane>>5)

#define Z 32
#define ROWS 65536
#define NBLK (ROWS / 128)        // 512 blocks: 4 tiles x 8 k-splits (8 waves)

#define NCHUNK 552               // quarters: 36 + 84 + 160 + 272
#define NGRAN (NCHUNK * 2)
#define NGP 1120                 // padded mg table (overreads -> 0)

typedef float f32x16 __attribute__((ext_vector_type(16)));
typedef _Float16 h2 __attribute__((ext_vector_type(2)));
typedef _Float16 h8 __attribute__((ext_vector_type(8)));

// cvt_pkrtz returns __fp16x2 — bit_cast to the _Float16 vector world
__device__ __forceinline__ h2 pkrtz(float a, float b) {
    return __builtin_bit_cast(h2, __builtin_amdgcn_cvt_pkrtz(a, b));
}

struct Sched {
    unsigned mg[NGP];          // (i*512) | (j*512)<<16 byte offs into zs[k][4][32]; pad=0
    short rt[NGRAN * 8];       // library row per (granule, jj), -1 = pad
    int nq[4];
};

constexpr Sched make_sched() {
    Sched s{};
    short gi[NGP] = {}, gj[NGP] = {};
    char gt[NGP] = {}, gq[NGP] = {};
    int tidx[32][32] = {}, pidx[32] = {};
    {
        int n = 0;
        for (int a = 0; a < 32; ++a)
            for (int b = a; b < 32; ++b) { tidx[a][b] = n; n += 32 - b; }
        for (int i = 0; i < 32; ++i) pidx[i] = i * 32 - i * (i - 1) / 2;
    }
    int g = 0;
    for (int q = 0; q < 4; ++q) {
        int g0 = g;
        // triples (a<=b): granule covers k in [8q,8q+8) for k>=b -> b>>3 <= q
        for (int b = 0; b < 32; ++b)
            if ((b >> 3) <= q)
                for (int a = 0; a <= b; ++a) { gi[g]=(short)a; gj[g]=(short)b; gt[g]=0; gq[g]=(char)q; ++g; }
        // pairs (b,32): theta = z_b*z_k, valid k<=b -> b>>3 >= q
        for (int b = 0; b < 32; ++b)
            if ((b >> 3) >= q) { gi[g]=(short)b; gj[g]=32; gt[g]=1; gq[g]=(char)q; ++g; }
        // linear: theta = z_k
        gi[g]=32; gj[g]=32; gt[g]=2; gq[g]=(char)q; ++g;
        // pad quarter to a multiple of 8 granules (4 chunks)
        while ((g - g0) & 7) { gi[g]=32; gj[g]=32; gt[g]=3; gq[g]=(char)q; ++g; }
        s.nq[q] = (g - g0) / 2;
    }
    for (int gg = 0; gg < NGRAN; ++gg) {
        s.mg[gg] = ((unsigned)gi[gg] * 512u) | (((unsigned)gj[gg] * 512u) << 16);
        int i = gi[gg], j = gj[gg], ty = gt[gg], q = gq[gg];
        for (int jj = 0; jj < 8; ++jj) {
            int k = 8 * q + jj, row = -1;
            if (ty == 0)      { if (k >= j) row = 561 + tidx[i][j] + (k - j); }   // triple (i,j,k)
            else if (ty == 1) { if (k <= i) row = 33 + pidx[k] + (i - k); }       // pair (k,i)
            else if (ty == 2) { row = 1 + k; }                                    // linear z_k
            s.rt[gg * 8 + jj] = (short)row;
        }
    }
    // [NGRAN,NGP): mg stays 0 -> pipeline overreads hit zs[0][0][m], never used
    return s;
}
constexpr Sched S = make_sched();
static_assert(S.nq[0] == 36 && S.nq[1] == 84 && S.nq[2] == 160 && S.nq[3] == 272, "chunk counts");

// ---- prep (R7-proven structure): coalesced, block per 4 granules; B -> fp16 RNE ----
__global__ void sindy_prep(const float* __restrict__ Xi,
                           const float* __restrict__ Xi_mask,
                           uint2* __restrict__ Bp2, size_t ws_size) {
    __shared__ unsigned short sh[8][32];
    const int tid = threadIdx.x;
    const int jj = tid >> 5, n = tid & 31;
#pragma unroll
    for (int pass = 0; pass < 4; ++pass) {
        int g = blockIdx.x * 4 + pass;
        int row = S.rt[g * 8 + jj];
        float f = 0.0f;
        if (row >= 0) f = Xi[row * Z + n] * Xi_mask[row * Z + n];
        _Float16 hh = (_Float16)f;                       // RNE f32->f16
        sh[jj][n] = __builtin_bit_cast(unsigned short, hh);
        __syncthreads();
        if (tid < 64) {
            int n2 = tid & 31, rep = tid >> 5;
            unsigned v0 = sh[4*rep+0][n2], v1 = sh[4*rep+1][n2];
            unsigned v2 = sh[4*rep+2][n2], v3 = sh[4*rep+3][n2];
            int c = g >> 1, h = g & 1;
            size_t idx = ((size_t)c * 64 + h * 32 + n2) * 2 + rep;
            if ((idx + 1) * 8 <= ws_size)
                Bp2[idx] = uint2{v0 | (v1 << 16), v2 | (v3 << 16)};
        }
        __syncthreads();
    }
}

// ---- main: block = 4 tiles x 8 k-splits (512 threads); 2 blocks/CU ----
__global__ __launch_bounds__(512, 4) void sindy_mfma(const float* __restrict__ z,
                                                     const float* __restrict__ Xi,
                                                     const float* __restrict__ Xi_mask,
                                                     const uint4* __restrict__ Bp,
                                                     float* __restrict__ out) {
    const int lane = threadIdx.x & 63;
    const int kh = threadIdx.x >> 6;     // k-split 0..7 (= wave id)
    const int m = lane & 31;
    const int half = lane >> 5;
    const long R = (long)blockIdx.x * 128;  // rows: 4 tiles of 32

    __shared__ float zs[33][4][32];      // interleaved: zs[k][tile][m]; bank = m
    __shared__ float cs_lo[4][32][32];   // combine chain kh3->kh1
    __shared__ float cs_hi[4][32][32];   // combine chain kh7->kh4
    __shared__ unsigned mg_sh[NGP];

    for (int t = threadIdx.x; t < NGP; t += 512) mg_sh[t] = S.mg[t];
    // stage z for 128 rows (coalesced float4 reads)
    for (int idx = threadIdx.x; idx < 1024; idx += 512) {
        int row = idx >> 3, q4 = idx & 7;
        float4 v = ((const float4*)(z + (R + row) * Z))[q4];
        int t = row >> 5, mm = row & 31;
        zs[4*q4+0][t][mm] = v.x; zs[4*q4+1][t][mm] = v.y;
        zs[4*q4+2][t][mm] = v.z; zs[4*q4+3][t][mm] = v.w;
    }
    if (threadIdx.x < 128) zs[32][threadIdx.x >> 5][threadIdx.x & 31] = 1.0f;  // z~[32]=1
    __syncthreads();

    // even, quarter-compatible k-cuts: {0,70,138,208,276,346,414,484,552}
    constexpr int c0_tab[8] = {0, 70, 138, 208, 276, 346, 414, 484};
    const int c0 = c0_tab[kh];
    const char* zmb = (const char*)&zs[0][0][0] + 4 * m;   // tile t at +128*t
    const unsigned* mgh = mg_sh + half;
    const uint4* bpl = Bp + lane;

    // products for one mg word, all 4 tiles
    auto zprod4 = [&](unsigned ws, float& t0, float& t1, float& t2, float& t3) {
        const char* bi = zmb + (ws & 0xFFFFu);
        const char* bj = zmb + (ws >> 16);
        t0 = *(const float*)(bi +   0) * *(const float*)(bj +   0);
        t1 = *(const float*)(bi + 128) * *(const float*)(bj + 128);
        t2 = *(const float*)(bi + 256) * *(const float*)(bj + 256);
        t3 = *(const float*)(bi + 384) * *(const float*)(bj + 384);
    };

    // B register pipeline, depth 2 bodies x 2 chunks (4 chunks in flight)
    uint4 b00 = bpl[(size_t)(c0 + 0) * 64], b01 = bpl[(size_t)(c0 + 1) * 64];
    uint4 b10 = bpl[(size_t)(c0 + 2) * 64], b11 = bpl[(size_t)(c0 + 3) * 64];

    // marching pointers (strength-reduced; no clamps in the loop)
    const uint4* bptr = bpl + (size_t)(c0 + 4) * 64;   // chunks c+4,c+5 (imm 0/1024)
    const unsigned* mgp = mgh + 2 * c0 + 8;            // mg for body+2

    // prime: products for chunks c0,c0+1; mg words for c0+2,c0+3
    float pa0, pa1, pa2, pa3, pb0, pb1, pb2, pb3;
    {
        unsigned u0 = mgh[2*c0+0], u1 = mgh[2*c0+2];
        zprod4(u0, pa0, pa1, pa2, pa3);
        zprod4(u1, pb0, pb1, pb2, pb3);
    }
    unsigned w0s = mgh[2*c0+4], w1s = mgh[2*c0+6];

    f32x16 acc0 = {}, acc1 = {}, acc2 = {}, acc3 = {};

    auto seg = [&](int Q, int cbeg, int cfin, bool tail) {
        // this quarter's z octets for all 4 tiles, pre-packed to fp16 pairs
        // (RTZ). reg q: lo=k 2q, hi=k 2q+1; k stride 512B, tile stride 128B.
        const char* zq = zmb + Q * 4096;
        h2 zt0_0, zt0_1, zt0_2, zt0_3, zt1_0, zt1_1, zt1_2, zt1_3;
        h2 zt2_0, zt2_1, zt2_2, zt2_3, zt3_0, zt3_1, zt3_2, zt3_3;
        {
#define LDZ(t) \
            { float a0 = *(const float*)(zq + (t)*128 +    0), a1 = *(const float*)(zq + (t)*128 +  512); \
              float a2 = *(const float*)(zq + (t)*128 + 1024), a3 = *(const float*)(zq + (t)*128 + 1536); \
              float a4 = *(const float*)(zq + (t)*128 + 2048), a5 = *(const float*)(zq + (t)*128 + 2560); \
              float a6 = *(const float*)(zq + (t)*128 + 3072), a7 = *(const float*)(zq + (t)*128 + 3584); \
              zt##t##_0 = pkrtz(a0, a1); zt##t##_1 = pkrtz(a2, a3); \
              zt##t##_2 = pkrtz(a4, a5); zt##t##_3 = pkrtz(a6, a7); }
            LDZ(0) LDZ(1) LDZ(2) LDZ(3)
#undef LDZ
        }

#define MKMFMA(t, accv) \
        auto mfma##t = [&](float pp, const uint4& bv) { \
            h2 p2 = pkrtz(pp, pp); \
            union { h2 h[4]; h8 v; } a; \
            a.h[0] = p2 * zt##t##_0; a.h[1] = p2 * zt##t##_1; \
            a.h[2] = p2 * zt##t##_2; a.h[3] = p2 * zt##t##_3; \
            union { uint4 v; h8 h; } b; b.v = bv; \
            accv = __builtin_amdgcn_mfma_f32_32x32x16_f16(a.v, b.h, accv, 0, 0, 0); \
        };
        MKMFMA(0, acc0) MKMFMA(1, acc1) MKMFMA(2, acc2) MKMFMA(3, acc3)
#undef MKMFMA

        const int cend = tail ? cfin - 4 : cfin;
#pragma unroll 2
        for (int c = cbeg; c < cend; c += 2) {
            // top: issue loads for chunks c+4,c+5 — 2 bodies ahead.
            uint4 n0 = bptr[0], n1 = bptr[64];
            bptr += 128;
            // mg for body+2 (pad absorbs overread)
            unsigned nw0 = mgp[0], nw1 = mgp[2];
            mgp += 4;
            // z reads + products for body+1 (4 tiles x 2 chunks)
            float qa0, qa1, qa2, qa3, qb0, qb1, qb2, qb3;
            zprod4(w0s, qa0, qa1, qa2, qa3);
            zprod4(w1s, qb0, qb1, qb2, qb3);
            // 8 MFMAs: 2 chunks x 4 tiles, B shared per chunk
            mfma0(pa0, b00); mfma1(pa1, b00); mfma2(pa2, b00); mfma3(pa3, b00);
            mfma0(pb0, b01); mfma1(pb1, b01); mfma2(pb2, b01); mfma3(pb3, b01);
            // retire products + mg + rotate B pipeline
            pa0 = qa0; pa1 = qa1; pa2 = qa2; pa3 = qa3;
            pb0 = qb0; pb1 = qb1; pb2 = qb2; pb3 = qb3;
            w0s = nw0; w1s = nw1;
            b00 = b10; b01 = b11; b10 = n0; b11 = n1;
        }
        if (tail) {
            // peel body cfin-4 (chunks 548/549): no loads/mg; KEEP z staging
            float qa0, qa1, qa2, qa3, qb0, qb1, qb2, qb3;
            zprod4(w0s, qa0, qa1, qa2, qa3);
            zprod4(w1s, qb0, qb1, qb2, qb3);
            mfma0(pa0, b00); mfma1(pa1, b00); mfma2(pa2, b00); mfma3(pa3, b00);
            mfma0(pb0, b01); mfma1(pb1, b01); mfma2(pb2, b01); mfma3(pb3, b01);
            pa0 = qa0; pa1 = qa1; pa2 = qa2; pa3 = qa3;
            pb0 = qb0; pb1 = qb1; pb2 = qb2; pb3 = qb3;
            b00 = b10; b01 = b11;
            // peel final body cfin-2 (chunks 550/551): consume-only
            mfma0(pa0, b00); mfma1(pa1, b00); mfma2(pa2, b00); mfma3(pa3, b00);
            mfma0(pb0, b01); mfma1(pb1, b01); mfma2(pb2, b01); mfma3(pb3, b01);
        }
    };

    // per-wave k-range, cut into quarter-aligned pieces (all even length).
    // Quarter boundaries: 36, 120, 280.
    switch (kh) {
    case 0: seg(0,   0,  36, false); seg(1,  36,  70, false); break;
    case 1: seg(1,  70, 120, false); seg(2, 120, 138, false); break;
    case 2: seg(2, 138, 208, false); break;
    case 3: seg(2, 208, 276, false); break;
    case 4: seg(2, 276, 280, false); seg(3, 280, 346, false); break;
    case 5: seg(3, 346, 414, false); break;
    case 6: seg(3, 414, 484, false); break;
    default: seg(3, 484, 552, true); break;
    }

    // combine: two parallel chains + final.
    // hi: kh7 write, kh6/kh5/kh4 add (rounds 1-4)
    // lo: kh3 write, kh2/kh1 add (rounds 1-3)
    // final: kh0 = acc + lo + hi + bias (round 5)
#define CS_W(buf) \
        for (int r = 0; r < 16; ++r) { \
            int row = (r & 3) + 8 * (r >> 2) + 4 * half; \
            buf[0][row][m] = acc0[r]; buf[1][row][m] = acc1[r]; \
            buf[2][row][m] = acc2[r]; buf[3][row][m] = acc3[r]; }
#define CS_A(buf) \
        for (int r = 0; r < 16; ++r) { \
            int row = (r & 3) + 8 * (r >> 2) + 4 * half; \
            buf[0][row][m] += acc0[r]; buf[1][row][m] += acc1[r]; \
            buf[2][row][m] += acc2[r]; buf[3][row][m] += acc3[r]; }

    if (kh == 7) { CS_W(cs_hi) } else if (kh == 3) { CS_W(cs_lo) }
    __syncthreads();
    if (kh == 6) { CS_A(cs_hi) } else if (kh == 2) { CS_A(cs_lo) }
    __syncthreads();
    if (kh == 5) { CS_A(cs_hi) } else if (kh == 1) { CS_A(cs_lo) }
    __syncthreads();
    if (kh == 4) { CS_A(cs_hi) }
    __syncthreads();
    if (kh == 0) {
        const float bias = Xi[m] * Xi_mask[m];   // library row 0 (ones), col n = m
#pragma unroll
        for (int r = 0; r < 16; ++r) {
            int row = (r & 3) + 8 * (r >> 2) + 4 * half;
            out[(R +  0 + row) * Z + m] = acc0[r] + cs_lo[0][row][m] + cs_hi[0][row][m] + bias;
            out[(R + 32 + row) * Z + m] = acc1[r] + cs_lo[1][row][m] + cs_hi[1][row][m] + bias;
            out[(R + 64 + row) * Z + m] = acc2[r] + cs_lo[2][row][m] + cs_hi[2][row][m] + bias;
            out[(R + 96 + row) * Z + m] = acc3[r] + cs_lo[3][row][m] + cs_hi[3][row][m] + bias;
        }
    }
#undef CS_W
#undef CS_A
}

extern "C" void kernel_launch(void* const* d_in, const int* in_sizes, int n_in,
                              void* d_out, int out_size, void* d_ws, size_t ws_size,
                              hipStream_t stream) {
    const float* z       = (const float*)d_in[0];
    const float* Xi      = (const float*)d_in[1];
    const float* Xi_mask = (const float*)d_in[2];
    // d_in[3]=z_mean, d_in[4]=z_std: unused by the reference
    float* out = (float*)d_out;
    uint4* Bp  = (uint4*)d_ws;   // NCHUNK*64*16 = 565,248 bytes

    sindy_prep<<<NGRAN / 4, 256, 0, stream>>>(Xi, Xi_mask, (uint2*)d_ws, ws_size);
    sindy_mfma<<<NBLK, 512, 0, stream>>>(z, Xi, Xi_mask, Bp, out);
}

// Round 11
// 109.941 us; speedup vs baseline: 1.2276x; 1.2276x over previous
//
#include <hip/hip_runtime.h>

// SINDy: out[65536,32] = Theta(z)[65536,6545] @ (Xi*Xi_mask)[6545,32]
// Round-28: R26 (best, 45.4us) + depth-3 B register pipeline.
//  - R27 post-mortem: unified VGPR/AGPR budget = 512/waves-per-SIMD.
//    4-tile wave needs 64 AGPR + ~80 VGPR = 144 regs -> at 4 waves/SIMD
//    (128 cap) it SPILLED (WRITE_SIZE 8192->12288 KB = +4MB scratch).
//    4-tile + 4 waves/SIMD is structurally impossible; R26's 2 waves/SIMD
//    stands. Improve latency cover within it.
//  - Depth-2 -> depth-3 B prefetch (6 chunks in flight; issue-to-consume
//    ~2 bodies ~ 1600 cyc >> contended L2). Same lever as R22->R23 (+23%).
//    +32 VGPR -> ~112 of 256/wave budget at 2 waves/SIMD; no spill.
//  - kh3 peels THREE bodies (546/548/550); in-loop loads end at chunk 551.
//    peel1 keeps mg+zprod staging, peel2 keeps zprod, peel3 consume-only.
// MFMA 32x32x16 layouts (dtype-independent, verified rounds 1-14):
//   A[m][k]: m=lane&31, k=(lane>>5)*8+jj   (reg q: lo=k 2q, hi=k 2q+1)
//   B[k][n]: n=lane&31, k=(lane>>5)*8+jj
//   C/D:     col=lane&31, row=(reg&3)+8*(reg>>2)+4*(lane>>5)

#define Z 32
#define ROWS 65536
#define NBLK (ROWS / 128)        // 512 blocks: 4 tiles x 4 k-splits (4 waves)

#define NCHUNK 552               // quarters: 36 + 84 + 160 + 272
#define NGRAN (NCHUNK * 2)
#define NGP 1120                 // padded mg table (overreads -> 0)

typedef float f32x16 __attribute__((ext_vector_type(16)));
typedef _Float16 h2 __attribute__((ext_vector_type(2)));
typedef _Float16 h8 __attribute__((ext_vector_type(8)));

// cvt_pkrtz returns __fp16x2 — bit_cast to the _Float16 vector world
__device__ __forceinline__ h2 pkrtz(float a, float b) {
    return __builtin_bit_cast(h2, __builtin_amdgcn_cvt_pkrtz(a, b));
}

struct Sched {
    unsigned mg[NGP];          // (i*512) | (j*512)<<16 byte offs into zs[k][4][32]; pad=0
    short rt[NGRAN * 8];       // library row per (granule, jj), -1 = pad
    int nq[4];
};

constexpr Sched make_sched() {
    Sched s{};
    short gi[NGP] = {}, gj[NGP] = {};
    char gt[NGP] = {}, gq[NGP] = {};
    int tidx[32][32] = {}, pidx[32] = {};
    {
        int n = 0;
        for (int a = 0; a < 32; ++a)
            for (int b = a; b < 32; ++b) { tidx[a][b] = n; n += 32 - b; }
        for (int i = 0; i < 32; ++i) pidx[i] = i * 32 - i * (i - 1) / 2;
    }
    int g = 0;
    for (int q = 0; q < 4; ++q) {
        int g0 = g;
        // triples (a<=b): granule covers k in [8q,8q+8) for k>=b -> b>>3 <= q
        for (int b = 0; b < 32; ++b)
            if ((b >> 3) <= q)
                for (int a = 0; a <= b; ++a) { gi[g]=(short)a; gj[g]=(short)b; gt[g]=0; gq[g]=(char)q; ++g; }
        // pairs (b,32): theta = z_b*z_k, valid k<=b -> b>>3 >= q
        for (int b = 0; b < 32; ++b)
            if ((b >> 3) >= q) { gi[g]=(short)b; gj[g]=32; gt[g]=1; gq[g]=(char)q; ++g; }
        // linear: theta = z_k
        gi[g]=32; gj[g]=32; gt[g]=2; gq[g]=(char)q; ++g;
        // pad quarter to a multiple of 8 granules (4 chunks)
        while ((g - g0) & 7) { gi[g]=32; gj[g]=32; gt[g]=3; gq[g]=(char)q; ++g; }
        s.nq[q] = (g - g0) / 2;
    }
    for (int gg = 0; gg < NGRAN; ++gg) {
        s.mg[gg] = ((unsigned)gi[gg] * 512u) | (((unsigned)gj[gg] * 512u) << 16);
        int i = gi[gg], j = gj[gg], ty = gt[gg], q = gq[gg];
        for (int jj = 0; jj < 8; ++jj) {
            int k = 8 * q + jj, row = -1;
            if (ty == 0)      { if (k >= j) row = 561 + tidx[i][j] + (k - j); }   // triple (i,j,k)
            else if (ty == 1) { if (k <= i) row = 33 + pidx[k] + (i - k); }       // pair (k,i)
            else if (ty == 2) { row = 1 + k; }                                    // linear z_k
            s.rt[gg * 8 + jj] = (short)row;
        }
    }
    // [NGRAN,NGP): mg stays 0 -> pipeline overreads hit zs[0][0][m], never used
    return s;
}
constexpr Sched S = make_sched();
static_assert(S.nq[0] == 36 && S.nq[1] == 84 && S.nq[2] == 160 && S.nq[3] == 272, "chunk counts");

// ---- prep (R7-proven structure): coalesced, block per 4 granules; B -> fp16 RNE ----
__global__ void sindy_prep(const float* __restrict__ Xi,
                           const float* __restrict__ Xi_mask,
                           uint2* __restrict__ Bp2, size_t ws_size) {
    __shared__ unsigned short sh[8][32];
    const int tid = threadIdx.x;
    const int jj = tid >> 5, n = tid & 31;
#pragma unroll
    for (int pass = 0; pass < 4; ++pass) {
        int g = blockIdx.x * 4 + pass;
        int row = S.rt[g * 8 + jj];
        float f = 0.0f;
        if (row >= 0) f = Xi[row * Z + n] * Xi_mask[row * Z + n];
        _Float16 hh = (_Float16)f;                       // RNE f32->f16
        sh[jj][n] = __builtin_bit_cast(unsigned short, hh);
        __syncthreads();
        if (tid < 64) {
            int n2 = tid & 31, rep = tid >> 5;
            unsigned v0 = sh[4*rep+0][n2], v1 = sh[4*rep+1][n2];
            unsigned v2 = sh[4*rep+2][n2], v3 = sh[4*rep+3][n2];
            int c = g >> 1, h = g & 1;
            size_t idx = ((size_t)c * 64 + h * 32 + n2) * 2 + rep;
            if ((idx + 1) * 8 <= ws_size)
                Bp2[idx] = uint2{v0 | (v1 << 16), v2 | (v3 << 16)};
        }
        __syncthreads();
    }
}

// ---- main: block = 4 tiles x 4 k-splits; wave = ALL 4 tiles, one k-split ----
__global__ __launch_bounds__(256, 2) void sindy_mfma(const float* __restrict__ z,
                                                     const float* __restrict__ Xi,
                                                     const float* __restrict__ Xi_mask,
                                                     const uint4* __restrict__ Bp,
                                                     float* __restrict__ out) {
    const int lane = threadIdx.x & 63;
    const int kh = threadIdx.x >> 6;     // k-split 0..3 (= wave id)
    const int m = lane & 31;
    const int half = lane >> 5;
    const long R = (long)blockIdx.x * 128;  // rows: 4 tiles of 32

    __shared__ float zs[33][4][32];      // interleaved: zs[k][tile][m]; bank = m
    __shared__ float cs[4][32][32];      // sequential-add combine (4 tiles)
    __shared__ unsigned mg_sh[NGP];

    for (int t = threadIdx.x; t < NGP; t += 256) mg_sh[t] = S.mg[t];
    // stage z for 128 rows (coalesced float4 reads)
    for (int idx = threadIdx.x; idx < 1024; idx += 256) {
        int row = idx >> 3, q4 = idx & 7;
        float4 v = ((const float4*)(z + (R + row) * Z))[q4];
        int t = row >> 5, mm = row & 31;
        zs[4*q4+0][t][mm] = v.x; zs[4*q4+1][t][mm] = v.y;
        zs[4*q4+2][t][mm] = v.z; zs[4*q4+3][t][mm] = v.w;
    }
    if (threadIdx.x < 128) zs[32][threadIdx.x >> 5][threadIdx.x & 31] = 1.0f;  // z~[32]=1
    __syncthreads();

    const int c0 = kh * 138;
    const char* zmb = (const char*)&zs[0][0][0] + 4 * m;   // tile t at +128*t
    const unsigned* mgh = mg_sh + half;
    const uint4* bpl = Bp + lane;

    // products for one mg word, all 4 tiles
    auto zprod4 = [&](unsigned ws, float& t0, float& t1, float& t2, float& t3) {
        const char* bi = zmb + (ws & 0xFFFFu);
        const char* bj = zmb + (ws >> 16);
        t0 = *(const float*)(bi +   0) * *(const float*)(bj +   0);
        t1 = *(const float*)(bi + 128) * *(const float*)(bj + 128);
        t2 = *(const float*)(bi + 256) * *(const float*)(bj + 256);
        t3 = *(const float*)(bi + 384) * *(const float*)(bj + 384);
    };

    // B register pipeline, depth 3 bodies x 2 chunks (6 chunks in flight)
    uint4 b00 = bpl[(size_t)(c0 + 0) * 64], b01 = bpl[(size_t)(c0 + 1) * 64];
    uint4 b10 = bpl[(size_t)(c0 + 2) * 64], b11 = bpl[(size_t)(c0 + 3) * 64];
    uint4 b20 = bpl[(size_t)(c0 + 4) * 64], b21 = bpl[(size_t)(c0 + 5) * 64];

    // marching pointers (strength-reduced; no clamps in the loop)
    const uint4* bptr = bpl + (size_t)(c0 + 6) * 64;   // chunks c+6,c+7 (imm 0/1024)
    const unsigned* mgp = mgh + 2 * c0 + 8;            // mg for body+2

    // prime: products for chunks c0,c0+1; mg words for c0+2,c0+3
    float pa0, pa1, pa2, pa3, pb0, pb1, pb2, pb3;
    {
        unsigned u0 = mgh[2*c0+0], u1 = mgh[2*c0+2];
        zprod4(u0, pa0, pa1, pa2, pa3);
        zprod4(u1, pb0, pb1, pb2, pb3);
    }
    unsigned w0s = mgh[2*c0+4], w1s = mgh[2*c0+6];

    f32x16 acc0 = {}, acc1 = {}, acc2 = {}, acc3 = {};

    auto seg = [&](int Q, int cbeg, int cfin, bool tail) {
        // this quarter's z octets for all 4 tiles, pre-packed to fp16 pairs
        // (RTZ). reg q: lo=k 2q, hi=k 2q+1; k stride 512B, tile stride 128B.
        const char* zq = zmb + Q * 4096;
        h2 zt0_0, zt0_1, zt0_2, zt0_3, zt1_0, zt1_1, zt1_2, zt1_3;
        h2 zt2_0, zt2_1, zt2_2, zt2_3, zt3_0, zt3_1, zt3_2, zt3_3;
        {
#define LDZ(t) \
            { float a0 = *(const float*)(zq + (t)*128 +    0), a1 = *(const float*)(zq + (t)*128 +  512); \
              float a2 = *(const float*)(zq + (t)*128 + 1024), a3 = *(const float*)(zq + (t)*128 + 1536); \
              float a4 = *(const float*)(zq + (t)*128 + 2048), a5 = *(const float*)(zq + (t)*128 + 2560); \
              float a6 = *(const float*)(zq + (t)*128 + 3072), a7 = *(const float*)(zq + (t)*128 + 3584); \
              zt##t##_0 = pkrtz(a0, a1); zt##t##_1 = pkrtz(a2, a3); \
              zt##t##_2 = pkrtz(a4, a5); zt##t##_3 = pkrtz(a6, a7); }
            LDZ(0) LDZ(1) LDZ(2) LDZ(3)
#undef LDZ
        }

#define MKMFMA(t, accv) \
        auto mfma##t = [&](float pp, const uint4& bv) { \
            h2 p2 = pkrtz(pp, pp); \
            union { h2 h[4]; h8 v; } a; \
            a.h[0] = p2 * zt##t##_0; a.h[1] = p2 * zt##t##_1; \
            a.h[2] = p2 * zt##t##_2; a.h[3] = p2 * zt##t##_3; \
            union { uint4 v; h8 h; } b; b.v = bv; \
            accv = __builtin_amdgcn_mfma_f32_32x32x16_f16(a.v, b.h, accv, 0, 0, 0); \
        };
        MKMFMA(0, acc0) MKMFMA(1, acc1) MKMFMA(2, acc2) MKMFMA(3, acc3)
#undef MKMFMA

        const int cend = tail ? cfin - 6 : cfin;
#pragma unroll 2
        for (int c = cbeg; c < cend; c += 2) {
            // top: issue loads for chunks c+6,c+7 — 3 bodies ahead.
            uint4 n0 = bptr[0], n1 = bptr[64];
            bptr += 128;
            // mg for body+2 (pad absorbs overread)
            unsigned nw0 = mgp[0], nw1 = mgp[2];
            mgp += 4;
            // z reads + products for body+1 (4 tiles x 2 chunks)
            float qa0, qa1, qa2, qa3, qb0, qb1, qb2, qb3;
            zprod4(w0s, qa0, qa1, qa2, qa3);
            zprod4(w1s, qb0, qb1, qb2, qb3);
            // 8 MFMAs: 2 chunks x 4 tiles, B shared per chunk
            mfma0(pa0, b00); mfma1(pa1, b00); mfma2(pa2, b00); mfma3(pa3, b00);
            mfma0(pb0, b01); mfma1(pb1, b01); mfma2(pb2, b01); mfma3(pb3, b01);
            // retire products + mg + rotate B pipeline (3-stage)
            pa0 = qa0; pa1 = qa1; pa2 = qa2; pa3 = qa3;
            pb0 = qb0; pb1 = qb1; pb2 = qb2; pb3 = qb3;
            w0s = nw0; w1s = nw1;
            b00 = b10; b01 = b11; b10 = b20; b11 = b21; b20 = n0; b21 = n1;
        }
        if (tail) {
            // peel1 (c = cfin-6, chunks 546/547): mg + zprod staging, no loads
            {
                unsigned nw0 = mgp[0], nw1 = mgp[2];   // mg chunks 550/551 (in-bounds)
                float qa0, qa1, qa2, qa3, qb0, qb1, qb2, qb3;
                zprod4(w0s, qa0, qa1, qa2, qa3);
                zprod4(w1s, qb0, qb1, qb2, qb3);
                mfma0(pa0, b00); mfma1(pa1, b00); mfma2(pa2, b00); mfma3(pa3, b00);
                mfma0(pb0, b01); mfma1(pb1, b01); mfma2(pb2, b01); mfma3(pb3, b01);
                pa0 = qa0; pa1 = qa1; pa2 = qa2; pa3 = qa3;
                pb0 = qb0; pb1 = qb1; pb2 = qb2; pb3 = qb3;
                w0s = nw0; w1s = nw1;
                b00 = b10; b01 = b11; b10 = b20; b11 = b21;
            }
            // peel2 (chunks 548/549): zprod staging only
            {
                float qa0, qa1, qa2, qa3, qb0, qb1, qb2, qb3;
                zprod4(w0s, qa0, qa1, qa2, qa3);
                zprod4(w1s, qb0, qb1, qb2, qb3);
                mfma0(pa0, b00); mfma1(pa1, b00); mfma2(pa2, b00); mfma3(pa3, b00);
                mfma0(pb0, b01); mfma1(pb1, b01); mfma2(pb2, b01); mfma3(pb3, b01);
                pa0 = qa0; pa1 = qa1; pa2 = qa2; pa3 = qa3;
                pb0 = qb0; pb1 = qb1; pb2 = qb2; pb3 = qb3;
                b00 = b10; b01 = b11;
            }
            // peel3 (chunks 550/551): consume-only
            mfma0(pa0, b00); mfma1(pa1, b00); mfma2(pa2, b00); mfma3(pa3, b00);
            mfma0(pb0, b01); mfma1(pb1, b01); mfma2(pb2, b01); mfma3(pb3, b01);
        }
    };

    // quarter-aligned pieces of this wave's [c0, c0+138) range (all even)
    if (kh == 0)      { seg(0,   0,  36, false); seg(1,  36, 120, false); seg(2, 120, 138, false); }
    else if (kh == 1) { seg(2, 138, 276, false); }
    else if (kh == 2) { seg(2, 276, 280, false); seg(3, 280, 414, false); }
    else              { seg(3, 414, 552, true); }

    // sequential-add combine: kh3 writes, kh2/kh1 add, kh0 finishes
    if (kh == 3) {
#pragma unroll
        for (int r = 0; r < 16; ++r) {
            int row = (r & 3) + 8 * (r >> 2) + 4 * half;
            cs[0][row][m] = acc0[r]; cs[1][row][m] = acc1[r];
            cs[2][row][m] = acc2[r]; cs[3][row][m] = acc3[r];
        }
    }
    __syncthreads();
    if (kh == 2) {
#pragma unroll
        for (int r = 0; r < 16; ++r) {
            int row = (r & 3) + 8 * (r >> 2) + 4 * half;
            cs[0][row][m] += acc0[r]; cs[1][row][m] += acc1[r];
            cs[2][row][m] += acc2[r]; cs[3][row][m] += acc3[r];
        }
    }
    __syncthreads();
    if (kh == 1) {
#pragma unroll
        for (int r = 0; r < 16; ++r) {
            int row = (r & 3) + 8 * (r >> 2) + 4 * half;
            cs[0][row][m] += acc0[r]; cs[1][row][m] += acc1[r];
            cs[2][row][m] += acc2[r]; cs[3][row][m] += acc3[r];
        }
    }
    __syncthreads();
    if (kh == 0) {
        const float bias = Xi[m] * Xi_mask[m];   // library row 0 (ones), col n = m
#pragma unroll
        for (int r = 0; r < 16; ++r) {
            int row = (r & 3) + 8 * (r >> 2) + 4 * half;
            out[(R +  0 + row) * Z + m] = acc0[r] + cs[0][row][m] + bias;
            out[(R + 32 + row) * Z + m] = acc1[r] + cs[1][row][m] + bias;
            out[(R + 64 + row) * Z + m] = acc2[r] + cs[2][row][m] + bias;
            out[(R + 96 + row) * Z + m] = acc3[r] + cs[3][row][m] + bias;
        }
    }
}

extern "C" void kernel_launch(void* const* d_in, const int* in_sizes, int n_in,
                              void* d_out, int out_size, void* d_ws, size_t ws_size,
                              hipStream_t stream) {
    const float* z       = (const float*)d_in[0];
    const float* Xi      = (const float*)d_in[1];
    const float* Xi_mask = (const float*)d_in[2];
    // d_in[3]=z_mean, d_in[4]=z_std: unused by the reference
    float* out = (float*)d_out;
    uint4* Bp  = (uint4*)d_ws;   // NCHUNK*64*16 = 565,248 bytes

    sindy_prep<<<NGRAN / 4, 256, 0, stream>>>(Xi, Xi_mask, (uint2*)d_ws, ws_size);
    sindy_mfma<<<NBLK, 256, 0, stream>>>(z, Xi, Xi_mask, Bp, out);
}